// Round 9
// baseline (293.186 us; speedup 1.0000x reference)
//
#include <hip/hip_runtime.h>
#include <math.h>

#define NNODES 50000
#define NEDGE  800000
#define NG     3
#define D      128
#define GE     (NG*NEDGE)            // 2,400,000 combined edges
#define NBUK   782                   // buckets of 64 rows (row >> 6)
#define CH     4096                  // edges per k_bin block
#define NBLK   ((GE + CH - 1) / CH)  // 586
#define OS     (NBUK + 1)            // 783, off1 row stride
#define CAP2   3456                  // bucket record cap (mean 3069, exp-max ~3271)

// fp32 -> bf16 round-to-nearest-even (no NaN inputs here)
__device__ __forceinline__ unsigned short f2bf(float f) {
    unsigned u = __float_as_uint(f);
    return (unsigned short)((u + 0x7fffu + ((u >> 16) & 1u)) >> 16);
}

__device__ __forceinline__ int col_range(int c) {
    return (c >= 12500) + (c >= 25000) + (c >= 37500);
}

// ---------------------------------------------------------------------------
// K1: h = X @ W^T, stored as bf16 pairs [N, 64] uints (word k = dims 2k,2k+1).
// 64x64 tile, 256 thr, 4x4 reg tile. (proven r1-r8)
// ---------------------------------------------------------------------------
__global__ __launch_bounds__(256) void k_gemm(const float* __restrict__ X,
                                              const float* __restrict__ W,
                                              unsigned* __restrict__ hbits) {
    __shared__ float Xs[128 * 64];
    __shared__ float Ws[128 * 64];
    const int tid  = threadIdx.x;
    const int row0 = blockIdx.x * 64;
    const int col0 = blockIdx.y * 64;

    const int rl = tid & 63;
    const int kc = tid >> 6;
    int xr = row0 + rl; if (xr >= NNODES) xr = NNODES - 1;
    const float4* Xg = (const float4*)(X + (size_t)xr * D);
    const float4* Wg = (const float4*)(W + (size_t)(col0 + rl) * D);
#pragma unroll
    for (int it = 0; it < 8; ++it) {
        const int k4 = kc * 32 + it * 4;
        float4 xv = Xg[k4 >> 2];
        float4 wv = Wg[k4 >> 2];
        Xs[(k4 + 0) * 64 + rl] = xv.x;
        Xs[(k4 + 1) * 64 + rl] = xv.y;
        Xs[(k4 + 2) * 64 + rl] = xv.z;
        Xs[(k4 + 3) * 64 + rl] = xv.w;
        Ws[(k4 + 0) * 64 + rl] = wv.x;
        Ws[(k4 + 1) * 64 + rl] = wv.y;
        Ws[(k4 + 2) * 64 + rl] = wv.z;
        Ws[(k4 + 3) * 64 + rl] = wv.w;
    }
    __syncthreads();

    const int tx = tid & 15;
    const int ty = tid >> 4;
    float acc[4][4] = {};
    for (int k = 0; k < 128; ++k) {
        float4 xv4 = *(const float4*)&Xs[k * 64 + (ty << 2)];
        float4 wv4 = *(const float4*)&Ws[k * 64 + (tx << 2)];
        float xa[4] = {xv4.x, xv4.y, xv4.z, xv4.w};
        float wa[4] = {wv4.x, wv4.y, wv4.z, wv4.w};
#pragma unroll
        for (int i = 0; i < 4; ++i)
#pragma unroll
            for (int j = 0; j < 4; ++j)
                acc[i][j] += xa[i] * wa[j];
    }

#pragma unroll
    for (int i = 0; i < 4; ++i) {
        const int r = row0 + (ty << 2) + i;
        if (r < NNODES) {
            uint2 o;
            o.x = (unsigned)f2bf(acc[i][0]) | ((unsigned)f2bf(acc[i][1]) << 16);
            o.y = (unsigned)f2bf(acc[i][2]) | ((unsigned)f2bf(acc[i][3]) << 16);
            *(uint2*)&hbits[(size_t)r * 64 + ((col0 + (tx << 2)) >> 1)] = o;
        }
    }
}

// ---------------------------------------------------------------------------
// K2: per-block bucket binning, two global read passes, ~7KB LDS ->
// 8 blocks/CU occupancy (r8's 32KB LDS staging capped it at 3).
// (1) histogram bucket=row>>6 via int LDS atomics; (2) in-place scan;
// (3) claim rank, write record (row<<16|col, gate*val) bucket-grouped into
// the block's own 32KB out1 segment (L2-resident). ZERO global atomics.
// ---------------------------------------------------------------------------
__global__ __launch_bounds__(256) void k_bin(const int* __restrict__ rows,
                                             const int* __restrict__ cols,
                                             const float* __restrict__ vals,
                                             const float* __restrict__ alpha,
                                             uint2* __restrict__ out1,
                                             int* __restrict__ off1) {
    __shared__ int sA[1024];
    __shared__ int lcur[NBUK];
    const int t   = threadIdx.x;
    const int blk = blockIdx.x;
    const int start = blk * CH;
    const int end   = (start + CH < GE) ? (start + CH) : GE;

    const float g0 = 1.0f / (1.0f + __expf(-alpha[0]));
    const float g1 = 1.0f / (1.0f + __expf(-alpha[1]));
    const float g2 = 1.0f / (1.0f + __expf(-alpha[2]));

#pragma unroll
    for (int j = 0; j < 4; ++j) sA[t + j * 256] = 0;
    __syncthreads();

    // pass 1: bucket histogram
    for (int idx = start + t; idx < end; idx += 256)
        atomicAdd(&sA[rows[idx] >> 6], 1);
    __syncthreads();

    // in-place inclusive scan over 1024 (two barriers per step)
    for (int off = 1; off < 1024; off <<= 1) {
        int v[4];
#pragma unroll
        for (int j = 0; j < 4; ++j) {
            const int i = t + j * 256;
            v[j] = sA[i] + ((i >= off) ? sA[i - off] : 0);
        }
        __syncthreads();
#pragma unroll
        for (int j = 0; j < 4; ++j) sA[t + j * 256] = v[j];
        __syncthreads();
    }

    // exclusive offsets -> lcur + off1
    for (int b = t; b < NBUK; b += 256) {
        const int ex = b ? sA[b - 1] : 0;
        lcur[b] = ex;
        off1[(size_t)blk * OS + b] = ex;
    }
    if (t == 0) off1[(size_t)blk * OS + NBUK] = sA[NBUK - 1];
    __syncthreads();

    // pass 2: re-read (L2/L3-warm), claim rank, grouped write
    for (int idx = start + t; idx < end; idx += 256) {
        const int r = rows[idx];
        const int c = cols[idx];
        const float v = vals[idx];
        const float gv = v * (idx < NEDGE ? g0 : (idx < 2 * NEDGE ? g1 : g2));
        const int pos = atomicAdd(&lcur[r >> 6], 1);
        uint2 m;
        m.x = ((unsigned)r << 16) | (unsigned)c;   // both < 65536
        m.y = __float_as_uint(gv);
        out1[(size_t)blk * CH + pos] = m;
    }
}

// ---------------------------------------------------------------------------
// K3: one block (512 thr) per 64-row bucket; grid fully resident (4 blk/CU).
// (a) copy the bucket's mini-segments into LDS staging; (b) hist over
// key = local_row*4 + col_range (256 keys); scan; (c) build uint16
// permutation via LDS int-atomic claims; (d) aggregate in 4 COL-RANGE
// PHASES with a block barrier between phases: all 782 blocks process the
// same 3.2MB slice of h at a time -> per-XCD L2 (4MB) holds the slice ->
// h re-reads become L2 hits instead of L3 traffic. ZERO global atomics.
// ---------------------------------------------------------------------------
__global__ __launch_bounds__(512) void k_agg2(const unsigned* __restrict__ hbits,
                                              const uint2* __restrict__ out1,
                                              const int* __restrict__ off1,
                                              float* __restrict__ out) {
    __shared__ uint2 stg[CAP2];            // 27648 B
    __shared__ unsigned short order[CAP2]; //  6912 B
    __shared__ int sA[512];                //  2048 B
    __shared__ int rh2[256];               //  1024 B  counts per (lr,range)
    __shared__ int rb2[256];               //  1024 B  base per (lr,range)
    __shared__ int rc2[256];               //  1024 B  claim cursor
    const int t = threadIdx.x;
    const int b = blockIdx.x;

    if (t < 256) rh2[t] = 0;

    // my segments: k_bin blocks t and t+512
    const int s0 = off1[(size_t)t * OS + b];
    const int e0 = off1[(size_t)t * OS + b + 1];
    int s1 = 0, e1 = 0;
    int myLen = e0 - s0;
    if (t + 512 < NBLK) {
        s1 = off1[(size_t)(t + 512) * OS + b];
        e1 = off1[(size_t)(t + 512) * OS + b + 1];
        myLen += e1 - s1;
    }
    sA[t] = myLen;
    __syncthreads();

    // in-place inclusive 512-scan (two barriers per step)
    for (int off = 1; off < 512; off <<= 1) {
        const int v = sA[t] + ((t >= off) ? sA[t - off] : 0);
        __syncthreads();
        sA[t] = v;
        __syncthreads();
    }
    const int base = sA[t] - myLen;   // exclusive

    // copy segments -> LDS staging; hist over (lr, range) as we go
    {
        int p = base;
        const uint2* seg = out1 + (size_t)t * CH;
        for (int i = s0; i < e0; ++i, ++p) {
            if (p < CAP2) {
                const uint2 rec = seg[i];
                stg[p] = rec;
                const int key = (int)((rec.x >> 16) & 63u) * 4 + col_range((int)(rec.x & 0xffffu));
                atomicAdd(&rh2[key], 1);
            }
        }
        if (t + 512 < NBLK) {
            const uint2* seg2 = out1 + (size_t)(t + 512) * CH;
            for (int i = s1; i < e1; ++i, ++p) {
                if (p < CAP2) {
                    const uint2 rec = seg2[i];
                    stg[p] = rec;
                    const int key = (int)((rec.x >> 16) & 63u) * 4 + col_range((int)(rec.x & 0xffffu));
                    atomicAdd(&rh2[key], 1);
                }
            }
        }
    }
    __syncthreads();

    // exclusive 256-scan of rh2 (in-place, two barriers per step)
    if (t < 256) sA[t] = rh2[t];
    __syncthreads();
    for (int off = 1; off < 256; off <<= 1) {
        int v = 0;
        if (t < 256) v = sA[t] + ((t >= off) ? sA[t - off] : 0);
        __syncthreads();
        if (t < 256) sA[t] = v;
        __syncthreads();
    }
    if (t < 256) { rb2[t] = sA[t] - rh2[t]; rc2[t] = sA[t] - rh2[t]; }
    __syncthreads();

    // build permutation: claim rank per key, store uint16 index
    {
        const int lim = (base + myLen < CAP2) ? (base + myLen) : CAP2;
        for (int k = base; k < lim; ++k) {
            const uint2 rec = stg[k];
            const int key = (int)((rec.x >> 16) & 63u) * 4 + col_range((int)(rec.x & 0xffffu));
            const int pos = atomicAdd(&rc2[key], 1);
            order[pos] = (unsigned short)k;
        }
    }
    __syncthreads();

    // aggregate: wave w owns local rows w*8..w*8+7; 4 col-range phases with
    // block barriers so all blocks sweep the same h slice simultaneously.
    const int w    = t >> 6;
    const int lane = t & 63;
    float2 acc[8];
#pragma unroll
    for (int k = 0; k < 8; ++k) acc[k] = make_float2(0.f, 0.f);

    for (int rg = 0; rg < 4; ++rg) {
#pragma unroll
        for (int k = 0; k < 8; ++k) {
            const int lr  = (w << 3) + k;
            const int key = lr * 4 + rg;
            const int s   = rb2[key];
            const int cnt = rh2[key];
            float2 a = acc[k];
            int i = 0;
            for (; i + 8 <= cnt; i += 8) {
                int idx8[8];
#pragma unroll
                for (int j = 0; j < 8; ++j) idx8[j] = order[s + i + j];
                uint2 m[8];
#pragma unroll
                for (int j = 0; j < 8; ++j) m[j] = stg[idx8[j]];
                unsigned hb[8];
#pragma unroll
                for (int j = 0; j < 8; ++j)
                    hb[j] = hbits[(size_t)(m[j].x & 0xffffu) * 64 + lane];
#pragma unroll
                for (int j = 0; j < 8; ++j) {
                    const float v = __uint_as_float(m[j].y);
                    a.x += v * __uint_as_float(hb[j] << 16);
                    a.y += v * __uint_as_float(hb[j] & 0xffff0000u);
                }
            }
            for (; i < cnt; ++i) {
                const uint2 m = stg[order[s + i]];
                const unsigned hbv = hbits[(size_t)(m.x & 0xffffu) * 64 + lane];
                const float v = __uint_as_float(m.y);
                a.x += v * __uint_as_float(hbv << 16);
                a.y += v * __uint_as_float(hbv & 0xffff0000u);
            }
            acc[k] = a;
        }
        if (rg < 3) __syncthreads();   // phase alignment across the block
    }

#pragma unroll
    for (int k = 0; k < 8; ++k) {
        const int row = (b << 6) + (w << 3) + k;
        if (row < NNODES)
            ((float2*)out)[(size_t)row * 64 + lane] = acc[k];
    }
}

extern "C" void kernel_launch(void* const* d_in, const int* in_sizes, int n_in,
                              void* d_out, int out_size, void* d_ws, size_t ws_size,
                              hipStream_t stream) {
    const float* X     = (const float*)d_in[0];
    const float* W     = (const float*)d_in[1];
    const float* alpha = (const float*)d_in[2];
    const int*   rows  = (const int*)d_in[3];
    const int*   cols  = (const int*)d_in[4];
    const float* vals  = (const float*)d_in[5];
    float* out = (float*)d_out;

    // workspace layout
    char* ws = (char*)d_ws;
    unsigned* hbits = (unsigned*)(ws + 0);           // 12,800,000 B
    uint2*    out1  = (uint2*)  (ws + 12800000);     // 19,202,048 B (586*4096*8)
    int*      off1  = (int*)    (ws + 32002048);     //  1,835,352 B (586*783*4)
    // total: 33,837,400 B

    hipLaunchKernelGGL(k_gemm, dim3((NNODES + 63) / 64, 2), dim3(256), 0, stream, X, W, hbits);
    hipLaunchKernelGGL(k_bin, dim3(NBLK), dim3(256), 0, stream,
                       rows, cols, vals, alpha, out1, off1);
    hipLaunchKernelGGL(k_agg2, dim3(NBUK), dim3(512), 0, stream,
                       hbits, out1, off1, out);
}

// Round 10
// 239.380 us; speedup vs baseline: 1.2248x; 1.2248x over previous
//
#include <hip/hip_runtime.h>
#include <math.h>

#define NNODES 50000
#define NEDGE  800000
#define NG     3
#define D      128
#define GE     (NG*NEDGE)            // 2,400,000 combined edges
#define NBUK   782                   // buckets of 64 rows (row >> 6)
#define CH     4096                  // edges per k_bin block
#define NBLK   ((GE + CH - 1) / CH)  // 586
#define OS     (NBUK + 1)            // 783, off1 row stride
#define CAP2   3456                  // bucket record cap (mean 3069, exp-max ~3271)

typedef __attribute__((ext_vector_type(8))) short bf16x8;
typedef __attribute__((ext_vector_type(4))) float f32x4;

// fp32 -> bf16 round-to-nearest-even (no NaN inputs here)
__device__ __forceinline__ unsigned short f2bf(float f) {
    unsigned u = __float_as_uint(f);
    return (unsigned short)((u + 0x7fffu + ((u >> 16) & 1u)) >> 16);
}

// ---------------------------------------------------------------------------
// K0: swizzle W (fp32 [128][128], row=out) into bf16 MFMA B-fragment order:
// Wf[nt][kc][lane] = 8 bf16: W[nt*16 + (lane&15)][kc*32 + (lane>>4)*8 + j]
// One 16B record per (nt,kc,lane) -> gemm reads are coalesced ds_read_b128.
// ---------------------------------------------------------------------------
__global__ void k_wprep(const float* __restrict__ W, uint4* __restrict__ Wf) {
    const int t = threadIdx.x;   // 256 threads, 1 block
    for (int i = t; i < 2048; i += 256) {
        const int nt   = i >> 8;         // 0..7
        const int kc   = (i >> 6) & 3;   // 0..3
        const int lane = i & 63;
        const int n  = nt * 16 + (lane & 15);
        const int k0 = kc * 32 + (lane >> 4) * 8;
        const float* src = W + (size_t)n * 128 + k0;
        unsigned u0 = (unsigned)f2bf(src[0]) | ((unsigned)f2bf(src[1]) << 16);
        unsigned u1 = (unsigned)f2bf(src[2]) | ((unsigned)f2bf(src[3]) << 16);
        unsigned u2 = (unsigned)f2bf(src[4]) | ((unsigned)f2bf(src[5]) << 16);
        unsigned u3 = (unsigned)f2bf(src[6]) | ((unsigned)f2bf(src[7]) << 16);
        Wf[i] = make_uint4(u0, u1, u2, u3);
    }
}

// ---------------------------------------------------------------------------
// K1: h = X @ W^T via bf16 MFMA 16x16x32. Block = 256 thr = 4 waves, 64 rows.
// Wave w owns rows [blk*64 + w*16, +16). All of Wf (32KB) staged in LDS once.
// A-frag: lane holds X[m=lane&15][k=(lane>>4)*8+j] (m120-verified layout);
// B-frag: same shape from W rows (B^T input, as the verified gemm_bt ladder);
// C/D: col=lane&15, row=(lane>>4)*4+reg (m89/m91-verified).
// h stored as bf16 u16[row*128 + col] (same bytes the aggregator expects).
// ---------------------------------------------------------------------------
__global__ __launch_bounds__(256) void k_gemm(const float* __restrict__ X,
                                              const uint4* __restrict__ Wf,
                                              unsigned short* __restrict__ hb16) {
    __shared__ uint4 Wl[2048];   // 32KB
    const int t = threadIdx.x;
#pragma unroll
    for (int j = 0; j < 8; ++j) Wl[t + j * 256] = Wf[t + j * 256];
    __syncthreads();

    const int w    = t >> 6;
    const int lane = t & 63;
    const int q    = lane >> 4;
    const int ml   = lane & 15;
    const int m0   = blockIdx.x * 64 + w * 16;

    int xr = m0 + ml; if (xr >= NNODES) xr = NNODES - 1;   // clamp (stores guarded)
    const float* xrow = X + (size_t)xr * 128;

    bf16x8 xf[4];
#pragma unroll
    for (int kc = 0; kc < 4; ++kc) {
        const int k0 = kc * 32 + q * 8;
        float4 a = *(const float4*)(xrow + k0);
        float4 b = *(const float4*)(xrow + k0 + 4);
        bf16x8 v;
        v[0] = (short)f2bf(a.x); v[1] = (short)f2bf(a.y);
        v[2] = (short)f2bf(a.z); v[3] = (short)f2bf(a.w);
        v[4] = (short)f2bf(b.x); v[5] = (short)f2bf(b.y);
        v[6] = (short)f2bf(b.z); v[7] = (short)f2bf(b.w);
        xf[kc] = v;
    }

#pragma unroll
    for (int nt = 0; nt < 8; ++nt) {
        f32x4 acc = {0.f, 0.f, 0.f, 0.f};
#pragma unroll
        for (int kc = 0; kc < 4; ++kc) {
            const bf16x8 wf = *(const bf16x8*)&Wl[(nt * 4 + kc) * 64 + lane];
            acc = __builtin_amdgcn_mfma_f32_16x16x32_bf16(xf[kc], wf, acc, 0, 0, 0);
        }
#pragma unroll
        for (int r = 0; r < 4; ++r) {
            const int row = m0 + q * 4 + r;
            if (row < NNODES)
                hb16[(size_t)row * 128 + nt * 16 + ml] = f2bf(acc[r]);
        }
    }
}

// ---------------------------------------------------------------------------
// K2: per-block bucket binning, single global read pass (r8 structure) with
// HALVED LDS atomics: pass 1's atomicAdd return value IS the within-bucket
// rank (stored u16); pass 2 is pure base[b]+rank stores, no atomics.
// ---------------------------------------------------------------------------
__global__ __launch_bounds__(256) void k_bin(const int* __restrict__ rows,
                                             const int* __restrict__ cols,
                                             const float* __restrict__ vals,
                                             const float* __restrict__ alpha,
                                             uint2* __restrict__ out1,
                                             int* __restrict__ off1) {
    __shared__ uint2 stg[CH];              // 32768 B
    __shared__ unsigned short rnk[CH];     //  8192 B
    __shared__ int sA[1024];               //  4096 B
    const int t   = threadIdx.x;
    const int blk = blockIdx.x;
    const int start = blk * CH;
    const int end   = (start + CH < GE) ? (start + CH) : GE;

    const float g0 = 1.0f / (1.0f + __expf(-alpha[0]));
    const float g1 = 1.0f / (1.0f + __expf(-alpha[1]));
    const float g2 = 1.0f / (1.0f + __expf(-alpha[2]));

#pragma unroll
    for (int j = 0; j < 4; ++j) sA[t + j * 256] = 0;
    __syncthreads();

    // pass 1: read globals once, pack record into LDS, histogram + rank
    for (int idx = start + t, k = t; idx < end; idx += 256, k += 256) {
        const int r = rows[idx];
        const int c = cols[idx];
        const float v = vals[idx];
        const float gv = v * (idx < NEDGE ? g0 : (idx < 2 * NEDGE ? g1 : g2));
        uint2 rec;
        rec.x = ((unsigned)r << 16) | (unsigned)c;   // both < 65536
        rec.y = __float_as_uint(gv);
        stg[k] = rec;
        rnk[k] = (unsigned short)atomicAdd(&sA[r >> 6], 1);
    }
    __syncthreads();

    // in-place inclusive scan over 1024 (two barriers per step)
    for (int off = 1; off < 1024; off <<= 1) {
        int v[4];
#pragma unroll
        for (int j = 0; j < 4; ++j) {
            const int i = t + j * 256;
            v[j] = sA[i] + ((i >= off) ? sA[i - off] : 0);
        }
        __syncthreads();
#pragma unroll
        for (int j = 0; j < 4; ++j) sA[t + j * 256] = v[j];
        __syncthreads();
    }

    // off1 = exclusive offsets
    for (int b = t; b < NBUK; b += 256)
        off1[(size_t)blk * OS + b] = b ? sA[b - 1] : 0;
    if (t == 0) off1[(size_t)blk * OS + NBUK] = sA[NBUK - 1];

    // pass 2: position = base[bucket] + rank, grouped write, no atomics
    for (int idx = start + t, k = t; idx < end; idx += 256, k += 256) {
        const uint2 rec = stg[k];
        const int b = (int)(rec.x >> 22);            // row>>6
        const int pos = (b ? sA[b - 1] : 0) + (int)rnk[k];
        out1[(size_t)blk * CH + pos] = rec;
    }
}

// ---------------------------------------------------------------------------
// K3: one block (512 thr) per 64-row bucket (exact r8 version, proven 115us).
// Copy mini-segments into LDS; per-row hist+scan; uint16 permutation via
// int LDS atomic claims; 8 waves aggregate 8 rows each with unroll-8
// register gathers. ZERO global atomics.
// ---------------------------------------------------------------------------
__global__ __launch_bounds__(512) void k_agg2(const unsigned* __restrict__ hbits,
                                              const uint2* __restrict__ out1,
                                              const int* __restrict__ off1,
                                              float* __restrict__ out) {
    __shared__ uint2 stg[CAP2];            // 27648 B
    __shared__ unsigned short order[CAP2]; //  6912 B
    __shared__ int sA[512];                //  2048 B
    __shared__ int sB[512];                //  2048 B
    __shared__ int rh[64], rbase[64], rcur[64];
    const int t = threadIdx.x;
    const int b = blockIdx.x;

    if (t < 64) rh[t] = 0;

    const int s0 = off1[(size_t)t * OS + b];
    const int e0 = off1[(size_t)t * OS + b + 1];
    int s1 = 0, e1 = 0;
    int myLen = e0 - s0;
    if (t + 512 < NBLK) {
        s1 = off1[(size_t)(t + 512) * OS + b];
        e1 = off1[(size_t)(t + 512) * OS + b + 1];
        myLen += e1 - s1;
    }
    sA[t] = myLen;
    __syncthreads();

    int* src = sA; int* dst = sB;
    for (int off = 1; off < 512; off <<= 1) {
        dst[t] = src[t] + ((t >= off) ? src[t - off] : 0);
        __syncthreads();
        int* tmp = src; src = dst; dst = tmp;
    }
    const int base = src[t] - myLen;   // exclusive

    {
        int p = base;
        const uint2* seg = out1 + (size_t)t * CH;
        for (int i = s0; i < e0; ++i, ++p) {
            if (p < CAP2) {
                const uint2 rec = seg[i];
                stg[p] = rec;
                atomicAdd(&rh[(rec.x >> 16) & 63u], 1);
            }
        }
        if (t + 512 < NBLK) {
            const uint2* seg2 = out1 + (size_t)(t + 512) * CH;
            for (int i = s1; i < e1; ++i, ++p) {
                if (p < CAP2) {
                    const uint2 rec = seg2[i];
                    stg[p] = rec;
                    atomicAdd(&rh[(rec.x >> 16) & 63u], 1);
                }
            }
        }
    }
    __syncthreads();

    if (t < 64) sA[t] = rh[t];
    __syncthreads();
    for (int off = 1; off < 64; off <<= 1) {
        int v = 0;
        if (t < 64) v = sA[t] + ((t >= off) ? sA[t - off] : 0);
        __syncthreads();
        if (t < 64) sA[t] = v;
        __syncthreads();
    }
    if (t < 64) { rbase[t] = sA[t] - rh[t]; rcur[t] = sA[t] - rh[t]; }
    __syncthreads();

    {
        const int lim = (base + myLen < CAP2) ? (base + myLen) : CAP2;
        for (int k = base; k < lim; ++k) {
            const int lr = (int)((stg[k].x >> 16) & 63u);
            const int pos = atomicAdd(&rcur[lr], 1);
            order[pos] = (unsigned short)k;
        }
    }
    __syncthreads();

    const int w    = t >> 6;
    const int lane = t & 63;
    for (int k = 0; k < 8; ++k) {
        const int lr  = (w << 3) + k;
        const int row = (b << 6) + lr;
        const int s   = rbase[lr];
        const int cnt = rh[lr];
        float2 acc = make_float2(0.f, 0.f);
        int i = 0;
        for (; i + 8 <= cnt; i += 8) {
            int idx8[8];
#pragma unroll
            for (int j = 0; j < 8; ++j) idx8[j] = order[s + i + j];
            uint2 m[8];
#pragma unroll
            for (int j = 0; j < 8; ++j) m[j] = stg[idx8[j]];
            unsigned hb[8];
#pragma unroll
            for (int j = 0; j < 8; ++j)
                hb[j] = hbits[(size_t)(m[j].x & 0xffffu) * 64 + lane];
#pragma unroll
            for (int j = 0; j < 8; ++j) {
                const float v = __uint_as_float(m[j].y);
                acc.x += v * __uint_as_float(hb[j] << 16);
                acc.y += v * __uint_as_float(hb[j] & 0xffff0000u);
            }
        }
        for (; i < cnt; ++i) {
            const uint2 m = stg[order[s + i]];
            const unsigned hbv = hbits[(size_t)(m.x & 0xffffu) * 64 + lane];
            const float v = __uint_as_float(m.y);
            acc.x += v * __uint_as_float(hbv << 16);
            acc.y += v * __uint_as_float(hbv & 0xffff0000u);
        }
        if (row < NNODES)
            ((float2*)out)[(size_t)row * 64 + lane] = acc;
    }
}

extern "C" void kernel_launch(void* const* d_in, const int* in_sizes, int n_in,
                              void* d_out, int out_size, void* d_ws, size_t ws_size,
                              hipStream_t stream) {
    const float* X     = (const float*)d_in[0];
    const float* W     = (const float*)d_in[1];
    const float* alpha = (const float*)d_in[2];
    const int*   rows  = (const int*)d_in[3];
    const int*   cols  = (const int*)d_in[4];
    const float* vals  = (const float*)d_in[5];
    float* out = (float*)d_out;

    // workspace layout
    char* ws = (char*)d_ws;
    unsigned*       hbits = (unsigned*)(ws + 0);            // 12,800,000 B
    unsigned short* hb16  = (unsigned short*)(ws + 0);      // same bytes, u16 view
    uint2*          out1  = (uint2*)(ws + 12800000);        // 19,202,048 B
    int*            off1  = (int*)  (ws + 32002048);        //  1,835,352 B
    uint4*          Wf    = (uint4*)(ws + 33837408);        //     32,768 B
    // total: 33,870,176 B

    hipLaunchKernelGGL(k_wprep, dim3(1), dim3(256), 0, stream, W, Wf);
    hipLaunchKernelGGL(k_gemm, dim3(NBUK), dim3(256), 0, stream, X, Wf, hb16);
    hipLaunchKernelGGL(k_bin, dim3(NBLK), dim3(256), 0, stream,
                       rows, cols, vals, alpha, out1, off1);
    hipLaunchKernelGGL(k_agg2, dim3(NBUK), dim3(512), 0, stream,
                       hbits, out1, off1, out);
}